// Round 9
// baseline (822.433 us; speedup 1.0000x reference)
//
#include <hip/hip_runtime.h>
#include <math.h>

#define EPSV 1e-10f

typedef _Float16 f16x8 __attribute__((ext_vector_type(8)));
typedef _Float16 f16x4 __attribute__((ext_vector_type(4)));
typedef float f32x4 __attribute__((ext_vector_type(4)));

// ---------------- agg LDS layout (bytes) ----------------
#define OFF_W1T  0       // 16384: W1t[n][k] f16 swz      (P0: AU f32 64x64)
#define OFF_W2T  16384   // 8192:  W2t[n2][h] f16 swz
#define OFF_M2T  24576   // 8192:  M2t[n3][h] f16 swz (M2 = W2 . AW1x)
#define OFF_X    32768   // 32768: 8 wave-slots x 4096B: H tile rows (16 x 256B)
                         //        (P0: uS f32; P2a: cst partials 8x64 f32)
#define OFF_V    65536   // 8192:  sV[g][n], g < 32
#define SMEM_SZ  73728   // 2 blocks/CU (147456 <= 163840) -> 16 waves/CU

__device__ __forceinline__ f16x8 cvt_f16x8(const float4 a, const float4 b) {
  f16x8 h;
  h[0] = (_Float16)a.x; h[1] = (_Float16)a.y; h[2] = (_Float16)a.z; h[3] = (_Float16)a.w;
  h[4] = (_Float16)b.x; h[5] = (_Float16)b.y; h[6] = (_Float16)b.z; h[7] = (_Float16)b.w;
  return h;
}

// ---------------------------------------------------------------------------
// Fused item-aggregation. 512 thr = 8 waves, wave owns whole groups.
// S-blocks [0,640): 32 groups (P=40). Wave = 2 PAIRS of groups; each pair =
// 80 rows = 5 exact 16-row tiles (no padding): tiles 0-1 pure-A, tile 2 mixed
// (quads 0-1 = A rows 32-39, quads 2-3 = B rows 0-7), tiles 3-4 pure-B.
// I-blocks [640,704): 8 groups (P=100), 1 group/wave, 7 tiles (112 rows).
// Zero __syncthreads in the main loop; accumulators in registers.
// ---------------------------------------------------------------------------
__global__ __launch_bounds__(512, 4) void agg_kernel(
    const int nSblk,
    const int* __restrict__ idsS, const int* __restrict__ uidS,
    const int* __restrict__ idsI, const int* __restrict__ uidI,
    const float* __restrict__ user_table, const float* __restrict__ item_table,
    const float* __restrict__ rate_table,
    const float* __restrict__ gv_W1, const float* __restrict__ gv_b1,
    const float* __restrict__ gv_W2, const float* __restrict__ gv_b2,
    const float* __restrict__ atti_W1, const float* __restrict__ atti_b1,
    const float* __restrict__ atti_W2, const float* __restrict__ atti_b2,
    const float* __restrict__ agg_W, const float* __restrict__ agg_b,
    float* __restrict__ outS, float* __restrict__ outI) {
  __shared__ __align__(16) char smem[SMEM_SZ];
  const int tid = threadIdx.x;
  const int wave = tid >> 6, lane = tid & 63;
  const int quad = lane >> 4, mrow = lane & 15;

  const bool isS = (int)blockIdx.x < nSblk;
  const int NG = isS ? 32 : 8;
  const int P = isS ? 40 : 100;
  const int rowsplit = isS ? 40 : 112;  // pair-local row where group B starts
  const int* __restrict__ ids = isS ? idsS : idsI;
  const int* __restrict__ uidp = isS ? uidS : uidI;
  float* __restrict__ out = isS ? outS : outI;
  const int gbase = isS ? (int)blockIdx.x * 32 : ((int)blockIdx.x - nSblk) * 8;

  float* sV = (float*)(smem + OFF_V);
  char* smX = smem + OFF_X;
  char* smXw = smX + wave * 4096;  // wave-private H slot
  float* csW = (float*)smXw;       // epilogue c vector (H dead then)

  // ---- P0: uS (X region) + AU = AW1u^T f32 (W1T region, f4-swizzled) ----
  {
    float* uS = (float*)smX;
    float* AU = (float*)(smem + OFF_W1T);
    for (int t = tid; t < NG * 64; t += 512) {
      const int g = t >> 6, f = t & 63;
      uS[t] = user_table[(size_t)uidp[gbase + g] * 64 + f];
    }
    for (int o = tid; o < 1024; o += 512) {  // AU[j][k] = atti_W1[64+k][j]
      const int k = o >> 4, fb = o & 15;
      const float4 v = ((const float4*)(atti_W1 + (64 + k) * 64))[fb];
      const float* vp = (const float*)&v;
#pragma unroll
      for (int c = 0; c < 4; ++c) {
        const int j = fb * 4 + c;
        AU[j * 64 + (((k >> 2) ^ (j & 15)) << 2) + (k & 3)] = vp[c];
      }
    }
  }
  __syncthreads();
  // ---- P1: v[g][j] = u[g] . AW1u[:,j] ----
  {
    const float4* u4 = (const float4*)smX;
    const float4* a4 = (const float4*)(smem + OFF_W1T);
    for (int t = tid; t < NG * 64; t += 512) {
      const int g = t >> 6, j = t & 63;
      float s = 0.f;
#pragma unroll 4
      for (int kb = 0; kb < 16; ++kb) {
        const float4 uu = u4[g * 16 + kb];
        const float4 aa = a4[j * 16 + (kb ^ (j & 15))];
        s += uu.x * aa.x + uu.y * aa.y + uu.z * aa.z + uu.w * aa.w;
      }
      sV[t] = s;
    }
  }
  __syncthreads();
  // ---- P2a: W1T/W2T f16 staging (coalesced) + cst partials -> X ----
  {
    for (int o = tid; o < 2048; o += 512) {  // W1T[n][k], k in 0..127
      const int k = o >> 4, fb = o & 15;
      const float4 v = ((const float4*)(gv_W1 + k * 64))[fb];
      const float* vp = (const float*)&v;
#pragma unroll
      for (int c = 0; c < 4; ++c) {
        const int n = fb * 4 + c;
        *(_Float16*)(smem + OFF_W1T + n * 256 + ((((k >> 3) ^ (n & 7))) << 4) +
                     ((k & 7) << 1)) = (_Float16)vp[c];
      }
    }
    for (int o = tid; o < 1024; o += 512) {  // W2T[n2][h]
      const int h = o >> 4, fb = o & 15;
      const float4 v = ((const float4*)(gv_W2 + h * 64))[fb];
      const float* vp = (const float*)&v;
#pragma unroll
      for (int c = 0; c < 4; ++c) {
        const int n = fb * 4 + c;
        *(_Float16*)(smem + OFF_W2T + n * 128 + ((((h >> 3) ^ (n & 7))) << 4) +
                     ((h & 7) << 1)) = (_Float16)vp[c];
      }
    }
    // cst partials: p[jh][n] = sum_{j in jh*8..+8} b2[j]*AW1x[j][n]
    float* sCstP = (float*)smX;  // uS dead after P1
    const int n = tid & 63, jh = tid >> 6;  // jh in 0..7
    float p = 0.f;
#pragma unroll
    for (int jj = 0; jj < 8; ++jj) {
      const int j = jh * 8 + jj;
      p = fmaf(gv_b2[j], atti_W1[j * 64 + n], p);
    }
    sCstP[jh * 64 + n] = p;
  }
  // per-lane constant preloads (global, L2-hot)
  float b1r[16], b2v[4], aw2v[4];
#pragma unroll
  for (int nt = 0; nt < 4; ++nt) {
#pragma unroll
    for (int rg = 0; rg < 4; ++rg) b1r[nt * 4 + rg] = gv_b1[nt * 16 + quad * 4 + rg];
    b2v[nt] = gv_b2[nt * 16 + mrow];
    aw2v[nt] = atti_W2[nt * 16 + mrow];
  }
  const float ab2 = atti_b2[0];

  // ---- gather prefetch: lane's fragment = pair-row (tt*16+mrow), 4x8 floats ----
  float4 pf[8];
  float pm;
  auto do_pf = [&](int gA2, int gB2, int tt2) {
    const int rr = tt2 * 16 + mrow;
    const bool inB = rr >= rowsplit;
    const int g2 = inB ? gB2 : gA2;
    const int it = inB ? rr - rowsplit : rr;
    int iid = 0, rid = 0;
    float m = 0.f;
    if (it < P) {
      const int2 pr = ((const int2*)ids)[(size_t)g2 * P + it];
      iid = pr.x; rid = pr.y;
      m = pr.x > 0 ? 1.f : 0.f;
    }
    pm = m;
    const float* ib = item_table + (size_t)iid * 64 + quad * 8;
    const float* rb = rate_table + (size_t)rid * 64 + quad * 8;
    pf[0] = ((const float4*)ib)[0];        pf[1] = ((const float4*)ib)[1];
    pf[2] = ((const float4*)(ib + 32))[0]; pf[3] = ((const float4*)(ib + 32))[1];
    pf[4] = ((const float4*)rb)[0];        pf[5] = ((const float4*)rb)[1];
    pf[6] = ((const float4*)(rb + 32))[0]; pf[7] = ((const float4*)(rb + 32))[1];
  };
  {
    const int gA0 = isS ? gbase + wave * 4 : gbase + wave;
    do_pf(gA0, gA0 + (isS ? 1 : 0), 0);  // in flight across P2b
  }
  __syncthreads();  // B3: W1T/W2T/cstP ready
  // ---- P2b: M2T via MFMA (A,B from L2-hot global) + cstv to registers ----
  float cstv[4];
  {
    const int w4 = wave & 3;  // waves 4-7 duplicate (same bytes, benign)
    f16x8 aM[2];
#pragma unroll
    for (int ks = 0; ks < 2; ++ks) {
      f16x8 t;
#pragma unroll
      for (int j = 0; j < 8; ++j)
        t[j] = (_Float16)atti_W1[(ks * 32 + quad * 8 + j) * 64 + (w4 * 16 + mrow)];
      aM[ks] = t;
    }
#pragma unroll
    for (int ht = 0; ht < 4; ++ht) {
      f32x4 c = {0.f, 0.f, 0.f, 0.f};
#pragma unroll
      for (int ks = 0; ks < 2; ++ks) {
        const float* s = gv_W2 + (ht * 16 + mrow) * 64 + ks * 32 + quad * 8;
        f16x8 b;
#pragma unroll
        for (int j = 0; j < 8; ++j) b[j] = (_Float16)s[j];
        c = __builtin_amdgcn_mfma_f32_16x16x32_f16(aM[ks], b, c, 0, 0, 0);
      }
      const int h = ht * 16 + mrow;
#pragma unroll
      for (int rg = 0; rg < 4; ++rg) {
        const int n3 = w4 * 16 + quad * 4 + rg;
        *(_Float16*)(smem + OFF_M2T + n3 * 128 + ((((h >> 3) ^ (n3 & 7))) << 4) +
                     ((h & 7) << 1)) = (_Float16)c[rg];
      }
    }
    const float* sCstP = (const float*)smX;
#pragma unroll
    for (int nt = 0; nt < 4; ++nt) {
      const int n = nt * 16 + mrow;
      float cs = atti_b1[n];
#pragma unroll
      for (int jh = 0; jh < 8; ++jh) cs += sCstP[jh * 64 + n];
      cstv[nt] = cs;
    }
  }
  __syncthreads();  // B4: M2T ready; X region free for H tiles

  // ---- hoist W1 A-frags + M2 B-frags into registers (one-time) ----
  f16x8 aW[4][4], bMr[4][2];
#pragma unroll
  for (int nt = 0; nt < 4; ++nt) {
#pragma unroll
    for (int ks = 0; ks < 4; ++ks)
      aW[nt][ks] = *(const f16x8*)(smem + OFF_W1T + (nt * 16 + mrow) * 256 +
                                   (((ks * 4 + quad) ^ (mrow & 7)) << 4));
#pragma unroll
    for (int ks = 0; ks < 2; ++ks)
      bMr[nt][ks] = *(const f16x8*)(smem + OFF_M2T + (nt * 16 + mrow) * 128 +
                                    (((ks * 4 + quad) ^ (mrow & 7)) << 4));
  }

  // ---- per-pair state ----
  float vvA[4], vvB[4];
  float pnA[4], pnB[4], pdA, pdB;

  // tile body: mode 0 = all rows group A, 1 = mixed (quads 0-1 A, 2-3 B),
  // 2 = all B. (gAn,gBn,ttn) = next prefetch target.
  auto tile = [&](int mode, int gAn, int gBn, int ttn, bool dopf) {
    f16x8 bIn[4];
    bIn[0] = cvt_f16x8(pf[0], pf[1]);
    bIn[1] = cvt_f16x8(pf[2], pf[3]);
    bIn[2] = cvt_f16x8(pf[4], pf[5]);
    bIn[3] = cvt_f16x8(pf[6], pf[7]);
    const float mcur = pm;
    if (dopf) do_pf(gAn, gBn, ttn);
    // ---- layer1 (transposed): H^T -> b64 writes to wave-private slot ----
#pragma unroll
    for (int nt = 0; nt < 4; ++nt) {
      f32x4 c = {0.f, 0.f, 0.f, 0.f};
#pragma unroll
      for (int ks = 0; ks < 4; ++ks)
        c = __builtin_amdgcn_mfma_f32_16x16x32_f16(aW[nt][ks], bIn[ks], c, 0, 0, 0);
      f16x4 hv;
#pragma unroll
      for (int rg = 0; rg < 4; ++rg)
        hv[rg] = (_Float16)fmaxf(c[rg] + b1r[nt * 4 + rg], 0.f);
      *(f16x4*)(smXw + mrow * 256 +
                (((nt * 2 + (quad >> 1)) ^ (mrow & 7)) << 4) +
                ((quad & 1) << 3)) = hv;
    }
    // ---- H A-frags for layer2 + attention ----
    f16x8 a2[2];
#pragma unroll
    for (int ks = 0; ks < 2; ++ks)
      a2[ks] = *(const f16x8*)(smXw + mrow * 256 +
                               (((ks * 4 + quad) ^ (mrow & 7)) << 4));
    float mk[4];
#pragma unroll
    for (int rg = 0; rg < 4; ++rg) mk[rg] = __shfl(mcur, quad * 4 + rg);
    float vcur[4];
#pragma unroll
    for (int nt = 0; nt < 4; ++nt)
      vcur[nt] = (mode == 0) ? vvA[nt]
               : (mode == 2) ? vvB[nt]
                             : (quad < 2 ? vvA[nt] : vvB[nt]);
    f32x4 x2a[4];
    float tl[4] = {0.f, 0.f, 0.f, 0.f};
#pragma unroll
    for (int nt = 0; nt < 4; ++nt) {
      f32x4 c = {0.f, 0.f, 0.f, 0.f}, d = {0.f, 0.f, 0.f, 0.f};
#pragma unroll
      for (int ks = 0; ks < 2; ++ks) {
        const f16x8 bW = *(const f16x8*)(smem + OFF_W2T + (nt * 16 + mrow) * 128 +
                                         (((ks * 4 + quad) ^ (mrow & 7)) << 4));
        c = __builtin_amdgcn_mfma_f32_16x16x32_f16(a2[ks], bW, c, 0, 0, 0);
      }
#pragma unroll
      for (int ks = 0; ks < 2; ++ks)
        d = __builtin_amdgcn_mfma_f32_16x16x32_f16(a2[ks], bMr[nt][ks], d, 0, 0, 0);
#pragma unroll
      for (int rg = 0; rg < 4; ++rg) x2a[nt][rg] = c[rg] + b2v[nt];
#pragma unroll
      for (int rg = 0; rg < 4; ++rg) {
        const float hh = fmaxf(d[rg] + cstv[nt] + mk[rg] * vcur[nt], 0.f);
        tl[rg] = fmaf(hh, aw2v[nt], tl[rg]);
      }
    }
    float eA[4], eB[4];
#pragma unroll
    for (int rg = 0; rg < 4; ++rg) {
      float t = tl[rg];
      t += __shfl_xor(t, 1); t += __shfl_xor(t, 2);
      t += __shfl_xor(t, 4); t += __shfl_xor(t, 8);
      const float ee = __expf(t + ab2) * mk[rg];
      eA[rg] = (mode == 0) ? ee : (mode == 2) ? 0.f : (quad < 2 ? ee : 0.f);
      eB[rg] = (mode == 2) ? ee : (mode == 0) ? 0.f : (quad < 2 ? 0.f : ee);
      pdA += eA[rg];
      pdB += eB[rg];
    }
#pragma unroll
    for (int nt = 0; nt < 4; ++nt) {
      if (mode != 2) {
        pnA[nt] = fmaf(eA[0], x2a[nt][0], pnA[nt]);
        pnA[nt] = fmaf(eA[1], x2a[nt][1], pnA[nt]);
        pnA[nt] = fmaf(eA[2], x2a[nt][2], pnA[nt]);
        pnA[nt] = fmaf(eA[3], x2a[nt][3], pnA[nt]);
      }
      if (mode != 0) {
        pnB[nt] = fmaf(eB[0], x2a[nt][0], pnB[nt]);
        pnB[nt] = fmaf(eB[1], x2a[nt][1], pnB[nt]);
        pnB[nt] = fmaf(eB[2], x2a[nt][2], pnB[nt]);
        pnB[nt] = fmaf(eB[3], x2a[nt][3], pnB[nt]);
      }
    }
  };

  auto flush = [&](int gg, float* pn, float pd) {
    float dsum = pd;
    dsum += __shfl_xor(dsum, 16); dsum += __shfl_xor(dsum, 32);
    const float rd = 1.f / (dsum + EPSV);
#pragma unroll
    for (int nt = 0; nt < 4; ++nt) {
      float s = pn[nt];
      s += __shfl_xor(s, 16); s += __shfl_xor(s, 32);
      if (quad == 0) csW[nt * 16 + mrow] = s * rd;
    }
    float acc = agg_b[lane];
#pragma unroll 8
    for (int k = 0; k < 64; ++k) acc = fmaf(csW[k], agg_W[k * 64 + lane], acc);
    out[(size_t)gg * 64 + lane] = fmaxf(acc, 0.f);
  };

  // =================== barrier-free main loop ===================
  if (isS) {
#pragma unroll
    for (int pi = 0; pi < 2; ++pi) {
      const int gA = gbase + wave * 4 + 2 * pi, gB = gA + 1;
      const int gl = wave * 4 + 2 * pi;
#pragma unroll
      for (int nt = 0; nt < 4; ++nt) {
        vvA[nt] = sV[gl * 64 + nt * 16 + mrow];
        vvB[nt] = sV[(gl + 1) * 64 + nt * 16 + mrow];
        pnA[nt] = 0.f; pnB[nt] = 0.f;
      }
      pdA = 0.f; pdB = 0.f;
      tile(0, gA, gB, 1, true);
      tile(0, gA, gB, 2, true);
      tile(1, gA, gB, 3, true);
      tile(2, gA, gB, 4, true);
      tile(2, gA + 2, gB + 2, 0, pi == 0);  // last: prefetch next pair
      flush(gA, pnA, pdA);
      flush(gB, pnB, pdB);
    }
  } else {
    const int gA = gbase + wave;
#pragma unroll
    for (int nt = 0; nt < 4; ++nt) {
      vvA[nt] = sV[wave * 64 + nt * 16 + mrow];
      vvB[nt] = 0.f;
      pnA[nt] = 0.f; pnB[nt] = 0.f;
    }
    pdA = 0.f; pdB = 0.f;
#pragma unroll
    for (int tt = 0; tt < 7; ++tt) tile(0, gA, gA, tt + 1, tt < 6);
    flush(gA, pnA, pdA);
  }
}

// ---------------- stage2 LDS layout (bytes) ----------------
#define S2_W1T 0       // 17408: attu_W1^T f16 [n][k], pitch 272 (bank-rotated)
#define S2_X   17408   // 8704:  2 waves x 16 rows x 272B
#define S2_E   26112   // 128:   2 x 16 f32
#define S2_MSK 26240   // 128:   2 x 16 f32
#define S2_HB  26368   // 1536:  2 x 192 f32 (concat/hidden ping-pong)
#define S2_SZ  27904

// ---------------------------------------------------------------------------
// Kernel 2: beta attention (MFMA) + h_iS + final 3-layer MLP.
// 256 blocks x 128 thr; wave w handles b = blockIdx*2 + w autonomously.
// ---------------------------------------------------------------------------
__global__ __launch_bounds__(128, 2) void stage2_kernel(
    const int* __restrict__ u_user_pad, const float* __restrict__ user_table,
    const float* __restrict__ hoI, const float* __restrict__ hiI,
    const float* __restrict__ attu_W1, const float* __restrict__ attu_b1,
    const float* __restrict__ attu_W2, const float* __restrict__ attu_b2,
    const float* __restrict__ aggn_W, const float* __restrict__ aggn_b,
    const float* __restrict__ cm_W1, const float* __restrict__ cm_b1,
    const float* __restrict__ cm_W2, const float* __restrict__ cm_b2,
    const float* __restrict__ cm_W3, const float* __restrict__ cm_b3,
    float* __restrict__ out) {
  __shared__ __align__(16) char smem[S2_SZ];
  const int tid = threadIdx.x;
  const int wave = tid >> 6, lane = tid & 63;
  const int quad = lane >> 4, mrow = lane & 15;
  const int b = (int)blockIdx.x * 2 + wave;

  char* sW1 = smem + S2_W1T;
  char* sXw = smem + S2_X + wave * 4352;
  float* sE = (float*)(smem + S2_E) + wave * 16;
  float* sM = (float*)(smem + S2_MSK) + wave * 16;
  float* sB = (float*)(smem + S2_HB) + wave * 192;

  for (int o = tid; o < 2048; o += 128) {
    const int k = o >> 4, fb = o & 15;
    const float4 v = ((const float4*)(attu_W1 + k * 64))[fb];
    const float* vp = (const float*)&v;
#pragma unroll
    for (int c = 0; c < 4; ++c) {
      const int n = fb * 4 + c;
      *(_Float16*)(sW1 + n * 272 + ((k >> 3) << 4) + ((k & 7) << 1)) = (_Float16)vp[c];
    }
  }
  float b1v[4], w2v[4];
#pragma unroll
  for (int nt = 0; nt < 4; ++nt) {
    b1v[nt] = attu_b1[nt * 16 + mrow];
    w2v[nt] = attu_W2[nt * 16 + mrow];
  }
  const float b2s = attu_b2[0];

  float4 pa[4], pb[4];
  float msk[4];
  auto pfn = [&](int tt) {
#pragma unroll
    for (int k = 0; k < 4; ++k) {
      const int u = lane + (k << 6);
      const int r = u >> 4, bb = u & 15;
      const int q = tt * 16 + r;
      const int qc = q < 40 ? q : 39;
      int uid = 0;
      float m = 0.f;
      if (q < 40) {
        uid = u_user_pad[b * 40 + q];
        m = uid > 0 ? 1.f : 0.f;
      }
      msk[k] = m;
      const float* src = (bb < 8)
                             ? hoI + ((size_t)b * 40 + qc) * 64 + bb * 8
                             : user_table + (size_t)uid * 64 + (bb - 8) * 8;
      pa[k] = ((const float4*)src)[0];
      pb[k] = ((const float4*)src)[1];
    }
  };
  pfn(0);
  __syncthreads();  // W1T ready

  float numer = 0.f, pden = 0.f;
  for (int tt = 0; tt < 3; ++tt) {
#pragma unroll
    for (int k = 0; k < 4; ++k) {
      const int u = lane + (k << 6);
      const int r = u >> 4, bb = u & 15;
      *(f16x8*)(sXw + r * 272 + (bb << 4)) = cvt_f16x8(pa[k], pb[k]);
      if (bb == 0) sM[r] = msk[k];
    }
    if (tt < 2) pfn(tt + 1);
    f16x8 a[4];
#pragma unroll
    for (int ks = 0; ks < 4; ++ks)
      a[ks] = *(const f16x8*)(sXw + mrow * 272 + ((ks * 4 + quad) << 4));
    float mk[4];
#pragma unroll
    for (int rg = 0; rg < 4; ++rg) mk[rg] = sM[quad * 4 + rg];
    float tl[4] = {0.f, 0.f, 0.f, 0.f};
#pragma unroll
    for (int nt = 0; nt < 4; ++nt) {
      f32x4 d = {0.f, 0.f, 0.f, 0.f};
      const int n = nt * 16 + mrow;
#pragma unroll
      for (int ks = 0; ks < 4; ++ks) {
        const f16x8 bW = *(const f16x8*)(sW1 + n * 272 + ((ks * 4 + quad) << 4));
        d = __builtin_amdgcn_mfma_f32_16x16x32_f16(a[ks], bW, d, 0, 0, 0);
      }
#pragma unroll
      for (int rg = 0; rg < 4; ++rg) {
        const float h = fmaxf(d[rg] + b1v[nt], 0.f);
        tl[rg] = fmaf(h, w2v[nt], tl[rg]);
      }
    }
    float e[4];
#pragma unroll
    for (int rg = 0; rg < 4; ++rg) {
      float t = tl[rg];
      t += __shfl_xor(t, 1); t += __shfl_xor(t, 2);
      t += __shfl_xor(t, 4); t += __shfl_xor(t, 8);
      e[rg] = __expf(t + b2s) * mk[rg];
      pden += e[rg];
    }
    if (mrow == 0) {
#pragma unroll
      for (int rg = 0; rg < 4; ++rg) sE[quad * 4 + rg] = e[rg];
    }
#pragma unroll 4
    for (int r = 0; r < 16; ++r) {
      const float er = sE[r];
      const float xv = (float)*(const _Float16*)(sXw + r * 272 + ((lane >> 3) << 4) +
                                                 ((lane & 7) << 1));
      numer = fmaf(er, xv, numer);
    }
  }
  pden += __shfl_xor(pden, 16);
  pden += __shfl_xor(pden, 32);
  const float hagg = numer / (pden + EPSV);

  sB[128 + lane] = hagg;
  sB[lane] = hiI[(size_t)b * 64 + lane];
  float acc = aggn_b[lane];
#pragma unroll 8
  for (int k = 0; k < 64; ++k) acc = fmaf(sB[128 + k], aggn_W[k * 64 + lane], acc);
  sB[64 + lane] = fmaxf(acc, 0.f);
  float c1 = cm_b1[lane];
#pragma unroll 8
  for (int k = 0; k < 128; ++k) c1 = fmaf(sB[k], cm_W1[k * 64 + lane], c1);
  sB[128 + lane] = fmaxf(c1, 0.f);
  float c2 = cm_b2[lane];
#pragma unroll 8
  for (int k = 0; k < 64; ++k) c2 = fmaf(sB[128 + k], cm_W2[k * 64 + lane], c2);
  sB[lane] = fmaxf(c2, 0.f);
  float c3 = cm_b3[lane];
#pragma unroll 8
  for (int k = 0; k < 64; ++k) c3 = fmaf(sB[k], cm_W3[k * 64 + lane], c3);
  out[(size_t)b * 64 + lane] = fmaxf(c3, 0.f);
}

extern "C" void kernel_launch(void* const* d_in, const int* in_sizes, int n_in,
                              void* d_out, int out_size, void* d_ws, size_t ws_size,
                              hipStream_t stream) {
  const int* uids = (const int*)d_in[0];
  const int* u_item_pad = (const int*)d_in[1];
  const int* u_user_pad = (const int*)d_in[2];
  const int* u_user_item_pad = (const int*)d_in[3];
  const float* user_table = (const float*)d_in[4];
  const float* item_table = (const float*)d_in[5];
  const float* rate_table = (const float*)d_in[6];
  const float* gv_W1 = (const float*)d_in[7];
  const float* gv_b1 = (const float*)d_in[8];
  const float* gv_W2 = (const float*)d_in[9];
  const float* gv_b2 = (const float*)d_in[10];
  const float* atti_W1 = (const float*)d_in[11];
  const float* atti_b1 = (const float*)d_in[12];
  const float* atti_W2 = (const float*)d_in[13];
  const float* atti_b2 = (const float*)d_in[14];
  const float* agg_W = (const float*)d_in[15];
  const float* agg_b = (const float*)d_in[16];
  const float* attu_W1 = (const float*)d_in[17];
  const float* attu_b1 = (const float*)d_in[18];
  const float* attu_W2 = (const float*)d_in[19];
  const float* attu_b2 = (const float*)d_in[20];
  const float* aggn_W = (const float*)d_in[21];
  const float* aggn_b = (const float*)d_in[22];
  const float* cm_W1 = (const float*)d_in[23];
  const float* cm_b1 = (const float*)d_in[24];
  const float* cm_W2 = (const float*)d_in[25];
  const float* cm_b2 = (const float*)d_in[26];
  const float* cm_W3 = (const float*)d_in[27];
  const float* cm_b3 = (const float*)d_in[28];
  float* out = (float*)d_out;

  float* hoI = (float*)d_ws;                 // 512*40*64 floats
  float* hiI = hoI + (size_t)512 * 40 * 64;  // 512*64 floats

  // Merged S (640 blocks x 32 groups, paired) + I (64 blocks x 8 groups).
  agg_kernel<<<640 + 64, 512, 0, stream>>>(
      640, u_user_item_pad, u_user_pad, u_item_pad, uids,
      user_table, item_table, rate_table,
      gv_W1, gv_b1, gv_W2, gv_b2,
      atti_W1, atti_b1, atti_W2, atti_b2,
      agg_W, agg_b, hoI, hiI);
  // Beta attention + h_iS + final MLP (wave-autonomous MFMA).
  stage2_kernel<<<256, 128, 0, stream>>>(u_user_pad, user_table, hoI, hiI,
                                         attu_W1, attu_b1, attu_W2, attu_b2,
                                         aggn_W, aggn_b,
                                         cm_W1, cm_b1, cm_W2, cm_b2, cm_W3, cm_b3,
                                         out);
}